// Round 1
// baseline (717.377 us; speedup 1.0000x reference)
//
#include <hip/hip_runtime.h>
#include <hip/hip_bf16.h>

// Problem constants
#define NB 256
#define NDF 768
#define NQ 96
#define NS 361
#define SP 384      // S padded to multiple of 32 (MFMA K / N tiling)
#define KC 32       // K-chunk for GEMM1 (one MFMA K)
#define LDT 40      // row stride (bf16 elems) of transposed staging tiles: 80B -> 2-way bank conflict only
#define LDP 392     // row stride (bf16 elems) of attn2/A rows: 784B = 196 words ≡ 4 mod 32 -> 2-way only

typedef short bf16x8_t __attribute__((ext_vector_type(8)));
typedef float f32x4_t __attribute__((ext_vector_type(4)));

// LDS layout (bytes), phases alias:
//  Phase GEMM1 staging:
//   sQhi [96][40]  : off 0      size 7680
//   sQlo           : off 7680   size 7680
//   sChi [384][40] : off 15360  size 30720
//   sClo           : off 46080  size 30720   (end 76800)
//  Phase softmax2 + GEMM2:
//   sP (attn bf16 [96][392]) : off 0      size 75264
//   pmax [96][8] f32         : off 75264  size 3072
//   psum [96][8] f32         : off 78336  size 3072
//   rowmax [96] f32          : off 81408  size 384
//   rowinv [96] f32          : off 81792  size 384
//   sA (ctx bf16 [64][392])  : off 82176  size 50176  (end 132352)
#define SMEM_BYTES 132352

__device__ __forceinline__ unsigned short f2bf(float x) {
    unsigned u = __float_as_uint(x);
    u += 0x7FFFu + ((u >> 16) & 1u);   // RNE
    return (unsigned short)(u >> 16);
}
__device__ __forceinline__ float bf2f(unsigned short h) {
    return __uint_as_float(((unsigned)h) << 16);
}

__global__ __launch_bounds__(512, 2) void fused_attn_kernel(
    const float* __restrict__ Qg, const float* __restrict__ Cg,
    float* __restrict__ Wout, float* __restrict__ Aout)
{
    extern __shared__ char smem[];
    unsigned short* sQhi = (unsigned short*)(smem);
    unsigned short* sQlo = (unsigned short*)(smem + 7680);
    unsigned short* sChi = (unsigned short*)(smem + 15360);
    unsigned short* sClo = (unsigned short*)(smem + 46080);
    unsigned short* sP   = (unsigned short*)(smem);          // aliases staging (later phase)
    float* pmax   = (float*)(smem + 75264);
    float* psum   = (float*)(smem + 78336);
    float* rowmax = (float*)(smem + 81408);
    float* rowinv = (float*)(smem + 81792);
    unsigned short* sA = (unsigned short*)(smem + 82176);

    const int b    = blockIdx.x;
    const int tid  = threadIdx.x;
    const int w    = tid >> 6;     // wave 0..7
    const int lane = tid & 63;
    const int ll   = lane & 15;    // fragment row/col select
    const int lg   = lane >> 4;    // k-group select

    const float* qg = Qg + (size_t)b * NDF * NQ;   // [768][96]
    const float* cg = Cg + (size_t)b * NDF * NS;   // [768][361]

    // ---------------- GEMM1: logits^T[q][s] = sum_d query[d][q]*ctx[d][s] ----------------
    // wave w owns s-tiles 3w..3w+2 (s in [48w, 48w+48)), all 6 q-tiles.
    f32x4_t acc[6][3];
#pragma unroll
    for (int i = 0; i < 6; ++i)
#pragma unroll
        for (int j = 0; j < 3; ++j) acc[i][j] = (f32x4_t)0.0f;

    const int sb = 48 * w;

    for (int k0 = 0; k0 < NDF; k0 += KC) {
        __syncthreads();   // previous chunk's readers done
        // stage query^T chunk [96][32] as hi/lo bf16
        for (int i = tid; i < KC * NQ; i += 512) {
            int dd = i / NQ, qq = i - dd * NQ;
            float x = qg[(k0 + dd) * NQ + qq];
            unsigned short h = f2bf(x);
            unsigned short l = f2bf(x - bf2f(h));
            sQhi[qq * LDT + dd] = h;
            sQlo[qq * LDT + dd] = l;
        }
        // stage ctx^T chunk [384][32] as hi/lo bf16 (pad s>=361 with 0)
        for (int i = tid; i < KC * SP; i += 512) {
            int dd = i / SP, ss = i - dd * SP;
            float x = (ss < NS) ? cg[(k0 + dd) * NS + ss] : 0.0f;
            unsigned short h = f2bf(x);
            unsigned short l = f2bf(x - bf2f(h));
            sChi[ss * LDT + dd] = h;
            sClo[ss * LDT + dd] = l;
        }
        __syncthreads();

        bf16x8_t Bhi[3], Blo[3];
#pragma unroll
        for (int nt = 0; nt < 3; ++nt) {
            int row = sb + 16 * nt + ll;
            Bhi[nt] = *(const bf16x8_t*)&sChi[row * LDT + lg * 8];
            Blo[nt] = *(const bf16x8_t*)&sClo[row * LDT + lg * 8];
        }
#pragma unroll
        for (int mt = 0; mt < 6; ++mt) {
            int row = 16 * mt + ll;
            bf16x8_t Ahi = *(const bf16x8_t*)&sQhi[row * LDT + lg * 8];
            bf16x8_t Alo = *(const bf16x8_t*)&sQlo[row * LDT + lg * 8];
#pragma unroll
            for (int nt = 0; nt < 3; ++nt) {
                // split-bf16: hi*hi + hi*lo + lo*hi  (lo*lo negligible)
                acc[mt][nt] = __builtin_amdgcn_mfma_f32_16x16x32_bf16(Ahi, Bhi[nt], acc[mt][nt], 0, 0, 0);
                acc[mt][nt] = __builtin_amdgcn_mfma_f32_16x16x32_bf16(Ahi, Blo[nt], acc[mt][nt], 0, 0, 0);
                acc[mt][nt] = __builtin_amdgcn_mfma_f32_16x16x32_bf16(Alo, Bhi[nt], acc[mt][nt], 0, 0, 0);
            }
        }
    }
    __syncthreads();   // staging region dead; safe to reuse as sP

    // zero attn bf16 buffer (incl. pad columns) for GEMM2's B operand
    for (int i = tid; i < NQ * LDP; i += 512) sP[i] = 0;

    // ---------------- softmax over q (per s) — entirely in registers ----------------
    // Lane's (nt,ll) fixes s; its 24 regs (mt,r) + groups via shfl_xor(16,32) cover all 96 q.
#pragma unroll
    for (int nt = 0; nt < 3; ++nt) {
        float m = -3.0e38f;
#pragma unroll
        for (int mt = 0; mt < 6; ++mt)
#pragma unroll
            for (int r = 0; r < 4; ++r) m = fmaxf(m, acc[mt][nt][r]);
        m = fmaxf(m, __shfl_xor(m, 16));
        m = fmaxf(m, __shfl_xor(m, 32));
        float s = 0.0f;
#pragma unroll
        for (int mt = 0; mt < 6; ++mt)
#pragma unroll
            for (int r = 0; r < 4; ++r) {
                float e = __expf(acc[mt][nt][r] - m);
                acc[mt][nt][r] = e;
                s += e;
            }
        s += __shfl_xor(s, 16);
        s += __shfl_xor(s, 32);
        float inv = 4.0f / s;       // fold TEMP1=4 here -> logits2
#pragma unroll
        for (int mt = 0; mt < 6; ++mt)
#pragma unroll
            for (int r = 0; r < 4; ++r) acc[mt][nt][r] *= inv;
        if (sb + 16 * nt + ll >= NS) {   // fake s: exclude from softmax2 (max and sum)
#pragma unroll
            for (int mt = 0; mt < 6; ++mt)
#pragma unroll
                for (int r = 0; r < 4; ++r) acc[mt][nt][r] = -INFINITY;
        }
    }

    // ---------------- softmax over s (per q) — cross-wave via LDS partials ----------------
#pragma unroll
    for (int mt = 0; mt < 6; ++mt)
#pragma unroll
        for (int r = 0; r < 4; ++r) {
            float m = fmaxf(acc[mt][0][r], fmaxf(acc[mt][1][r], acc[mt][2][r]));
#pragma unroll
            for (int off = 1; off < 16; off <<= 1) m = fmaxf(m, __shfl_xor(m, off));
            if (ll == 0) pmax[(16 * mt + 4 * lg + r) * 8 + w] = m;
        }
    __syncthreads();
    if (tid < NQ) {
        float m = pmax[tid * 8];
#pragma unroll
        for (int i = 1; i < 8; ++i) m = fmaxf(m, pmax[tid * 8 + i]);
        rowmax[tid] = m;
    }
    __syncthreads();
#pragma unroll
    for (int mt = 0; mt < 6; ++mt)
#pragma unroll
        for (int r = 0; r < 4; ++r) {
            float rm = rowmax[16 * mt + 4 * lg + r];
            float s = 0.0f;
#pragma unroll
            for (int nt = 0; nt < 3; ++nt) {
                float e = __expf(acc[mt][nt][r] - rm);   // -inf -> 0 for fake s
                acc[mt][nt][r] = e;
                s += e;
            }
#pragma unroll
            for (int off = 1; off < 16; off <<= 1) s += __shfl_xor(s, off);
            if (ll == 0) psum[(16 * mt + 4 * lg + r) * 8 + w] = s;
        }
    __syncthreads();
    if (tid < NQ) {
        float s = 0.0f;
#pragma unroll
        for (int i = 0; i < 8; ++i) s += psum[tid * 8 + i];
        rowinv[tid] = 1.0f / s;
    }
    __syncthreads();

    // finalize: write attn_map (fp32 global) + attn bf16 to LDS for GEMM2
    float* aout = Aout + (size_t)b * NQ * NS;
#pragma unroll
    for (int mt = 0; mt < 6; ++mt)
#pragma unroll
        for (int r = 0; r < 4; ++r) {
            int q = 16 * mt + 4 * lg + r;
            float inv = rowinv[q];
#pragma unroll
            for (int nt = 0; nt < 3; ++nt) {
                int s = sb + 16 * nt + ll;
                float v = acc[mt][nt][r] * inv;
                if (s < NS) {
                    aout[q * NS + s] = v;
                    sP[q * LDP + s] = f2bf(v);
                }
            }
        }

    // ---------------- GEMM2: out[d][q] = sum_s ctx[d][s]*attn[q][s] ----------------
    float* wout = Wout + (size_t)b * NDF * NQ;
    const int mt2 = w >> 1;          // m-tile (d) 0..3 within 64-row block
    const int ntb = (w & 1) * 3;     // n-tile base (q)
    for (int db = 0; db < NDF; db += 64) {
        __syncthreads();   // sP writes visible (first iter) / sA readers done (later iters)
        for (int i = tid; i < 64 * SP; i += 512) {
            int dd = i / SP, ss = i - dd * SP;
            float x = (ss < NS) ? cg[(db + dd) * NS + ss] : 0.0f;
            sA[dd * LDP + ss] = f2bf(x);
        }
        __syncthreads();
        f32x4_t acc2[3];
        acc2[0] = (f32x4_t)0.0f; acc2[1] = (f32x4_t)0.0f; acc2[2] = (f32x4_t)0.0f;
        for (int c = 0; c < 12; ++c) {
            bf16x8_t a = *(const bf16x8_t*)&sA[(16 * mt2 + ll) * LDP + 32 * c + lg * 8];
#pragma unroll
            for (int nt = 0; nt < 3; ++nt) {
                bf16x8_t bb = *(const bf16x8_t*)&sP[(16 * (ntb + nt) + ll) * LDP + 32 * c + lg * 8];
                acc2[nt] = __builtin_amdgcn_mfma_f32_16x16x32_bf16(a, bb, acc2[nt], 0, 0, 0);
            }
        }
#pragma unroll
        for (int nt = 0; nt < 3; ++nt)
#pragma unroll
            for (int r = 0; r < 4; ++r) {
                int d = db + 16 * mt2 + 4 * lg + r;
                int q = 16 * (ntb + nt) + ll;
                wout[d * NQ + q] = acc2[nt][r];
            }
    }
}

extern "C" void kernel_launch(void* const* d_in, const int* in_sizes, int n_in,
                              void* d_out, int out_size, void* d_ws, size_t ws_size,
                              hipStream_t stream) {
    const float* Qg = (const float*)d_in[0];
    const float* Cg = (const float*)d_in[1];
    float* Wout = (float*)d_out;
    float* Aout = Wout + (size_t)NB * NDF * NQ;   // outputs concatenated: weighted_context, attn_map

    // allow >64KB dynamic LDS (gfx950 has 160KB/CU); idempotent, ignore error
    (void)hipFuncSetAttribute((const void*)fused_attn_kernel,
                              hipFuncAttributeMaxDynamicSharedMemorySize, SMEM_BYTES);

    hipLaunchKernelGGL(fused_attn_kernel, dim3(NB), dim3(512), SMEM_BYTES, stream,
                       Qg, Cg, Wout, Aout);
}

// Round 2
// 253.463 us; speedup vs baseline: 2.8303x; 2.8303x over previous
//
#include <hip/hip_runtime.h>

// Problem constants
#define NB 256
#define NDF 768
#define NQ 96
#define NS 361
#define LDT 36      // transposed staging row stride (bf16): 72B = 18 words (gcd 2 w/ 32 banks -> 2-way, free); 8B aligned
#define LDP 392     // attn LDS row stride (bf16): 784B = 196 words = 4 mod 32 -> 2-way, free; 16B aligned

typedef short bf16x4_t __attribute__((ext_vector_type(4)));
typedef short bf16x8_t __attribute__((ext_vector_type(8)));
typedef float f32x4_t __attribute__((ext_vector_type(4)));
typedef float f32x4u_t __attribute__((ext_vector_type(4), aligned(4)));   // 4B-aligned vec load (legal on gfx9+)
typedef unsigned int u32x2_t __attribute__((ext_vector_type(2)));
typedef unsigned int u32x4_t __attribute__((ext_vector_type(4)));

// pack hi16 of two f32 bit patterns into one dword: [x1.hi16 | x0.hi16]  (1 v_perm_b32)
__device__ __forceinline__ unsigned pack_hi(unsigned u1, unsigned u0) {
    return __builtin_amdgcn_perm(u1, u0, 0x07060302u);
}

__device__ __forceinline__ bf16x8_t ld8(const unsigned short* p) {   // two ds_read_b64 (8B aligned)
    bf16x4_t a = *(const bf16x4_t*)p;
    bf16x4_t b = *(const bf16x4_t*)(p + 4);
    bf16x8_t r;
    r[0] = a[0]; r[1] = a[1]; r[2] = a[2]; r[3] = a[3];
    r[4] = b[0]; r[5] = b[1]; r[6] = b[2]; r[7] = b[3];
    return r;
}

// ---------------- K1: GEMM1 (split-bf16) + softmax over q, writes 4*softmax_q into Aout ----------------
// grid = (NB*2): block = (batch, s-half of 192). 384 threads = 6 waves; wave owns 2 s-tiles x 6 q-tiles.
__global__ __launch_bounds__(384, 3) void k1_gemm1_softmaxq(
    const float* __restrict__ Qg, const float* __restrict__ Cg, float* __restrict__ Aout)
{
    __shared__ unsigned short sQhi[NQ * LDT];
    __shared__ unsigned short sQlo[NQ * LDT];
    __shared__ unsigned short sShi[192 * LDT];
    __shared__ unsigned short sSlo[192 * LDT];

    const int b  = blockIdx.x >> 1;
    const int h  = blockIdx.x & 1;
    const int tid  = threadIdx.x;
    const int wv   = tid >> 6;
    const int lane = tid & 63;
    const int ll = lane & 15;
    const int lg = lane >> 4;
    const int s0 = 192 * h;

    const float* __restrict__ qg = Qg + (size_t)b * NDF * NQ;   // [768][96]
    const float* __restrict__ cg = Cg + (size_t)b * NDF * NS;   // [768][361]

    f32x4_t acc[6][2];
#pragma unroll
    for (int i = 0; i < 6; ++i)
#pragma unroll
        for (int j = 0; j < 2; ++j) acc[i][j] = (f32x4_t)0.0f;

    for (int k0 = 0; k0 < NDF; k0 += 32) {
        __syncthreads();   // previous chunk's fragment readers done
        // stage query^T chunk: quad = (4 k-rows, 1 q). 8*96 = 768 quads.
#pragma unroll
        for (int j = 0; j < 2; ++j) {
            int it = j * 384 + tid;
            int kq = it / NQ;
            int qq = it - kq * NQ;
            const float* p = qg + (k0 + 4 * kq) * NQ + qq;
            float x0 = p[0], x1 = p[NQ], x2 = p[2 * NQ], x3 = p[3 * NQ];
            unsigned u0 = __float_as_uint(x0), u1 = __float_as_uint(x1);
            unsigned u2 = __float_as_uint(x2), u3 = __float_as_uint(x3);
            float l0 = x0 - __uint_as_float(u0 & 0xFFFF0000u);
            float l1 = x1 - __uint_as_float(u1 & 0xFFFF0000u);
            float l2 = x2 - __uint_as_float(u2 & 0xFFFF0000u);
            float l3 = x3 - __uint_as_float(u3 & 0xFFFF0000u);
            u32x2_t hi, lo;
            hi[0] = pack_hi(u1, u0); hi[1] = pack_hi(u3, u2);
            lo[0] = pack_hi(__float_as_uint(l1), __float_as_uint(l0));
            lo[1] = pack_hi(__float_as_uint(l3), __float_as_uint(l2));
            int off = qq * LDT + 4 * kq;
            *(u32x2_t*)&sQhi[off] = hi;
            *(u32x2_t*)&sQlo[off] = lo;
        }
        // stage ctx^T chunk: quad = (4 k-rows, 1 s). 8*192 = 1536 quads.
#pragma unroll
        for (int j = 0; j < 4; ++j) {
            int it = j * 384 + tid;
            int kq = it / 192;
            int ss = it - kq * 192;
            int s  = s0 + ss;
            bool ok = (s < NS);
            const float* p = cg + (k0 + 4 * kq) * NS + s;
            float x0 = ok ? p[0] : 0.0f;
            float x1 = ok ? p[NS] : 0.0f;
            float x2 = ok ? p[2 * NS] : 0.0f;
            float x3 = ok ? p[3 * NS] : 0.0f;
            unsigned u0 = __float_as_uint(x0), u1 = __float_as_uint(x1);
            unsigned u2 = __float_as_uint(x2), u3 = __float_as_uint(x3);
            float l0 = x0 - __uint_as_float(u0 & 0xFFFF0000u);
            float l1 = x1 - __uint_as_float(u1 & 0xFFFF0000u);
            float l2 = x2 - __uint_as_float(u2 & 0xFFFF0000u);
            float l3 = x3 - __uint_as_float(u3 & 0xFFFF0000u);
            u32x2_t hi, lo;
            hi[0] = pack_hi(u1, u0); hi[1] = pack_hi(u3, u2);
            lo[0] = pack_hi(__float_as_uint(l1), __float_as_uint(l0));
            lo[1] = pack_hi(__float_as_uint(l3), __float_as_uint(l2));
            int off = ss * LDT + 4 * kq;
            *(u32x2_t*)&sShi[off] = hi;
            *(u32x2_t*)&sSlo[off] = lo;
        }
        __syncthreads();

        bf16x8_t Bhi[2], Blo[2];
#pragma unroll
        for (int nt = 0; nt < 2; ++nt) {
            int row = 32 * wv + 16 * nt + ll;
            Bhi[nt] = ld8(&sShi[row * LDT + 8 * lg]);
            Blo[nt] = ld8(&sSlo[row * LDT + 8 * lg]);
        }
#pragma unroll
        for (int mt = 0; mt < 6; ++mt) {
            int row = 16 * mt + ll;
            bf16x8_t Ahi = ld8(&sQhi[row * LDT + 8 * lg]);
            bf16x8_t Alo = ld8(&sQlo[row * LDT + 8 * lg]);
#pragma unroll
            for (int nt = 0; nt < 2; ++nt) {
                acc[mt][nt] = __builtin_amdgcn_mfma_f32_16x16x32_bf16(Ahi, Bhi[nt], acc[mt][nt], 0, 0, 0);
                acc[mt][nt] = __builtin_amdgcn_mfma_f32_16x16x32_bf16(Ahi, Blo[nt], acc[mt][nt], 0, 0, 0);
                acc[mt][nt] = __builtin_amdgcn_mfma_f32_16x16x32_bf16(Alo, Bhi[nt], acc[mt][nt], 0, 0, 0);
            }
        }
    }

    // softmax over q (per s-col), fold *4; D layout: col(s)=ll, row(q)=16mt+4lg+r
#pragma unroll
    for (int nt = 0; nt < 2; ++nt) {
        float m = -3.0e38f;
#pragma unroll
        for (int mt = 0; mt < 6; ++mt)
#pragma unroll
            for (int r = 0; r < 4; ++r) m = fmaxf(m, acc[mt][nt][r]);
        m = fmaxf(m, __shfl_xor(m, 16));
        m = fmaxf(m, __shfl_xor(m, 32));
        float sum = 0.0f;
#pragma unroll
        for (int mt = 0; mt < 6; ++mt)
#pragma unroll
            for (int r = 0; r < 4; ++r) {
                float e = __expf(acc[mt][nt][r] - m);
                acc[mt][nt][r] = e;
                sum += e;
            }
        sum += __shfl_xor(sum, 16);
        sum += __shfl_xor(sum, 32);
        float inv = 4.0f / sum;     // fold TEMP1
#pragma unroll
        for (int mt = 0; mt < 6; ++mt)
#pragma unroll
            for (int r = 0; r < 4; ++r) acc[mt][nt][r] *= inv;
    }

    float* aout = Aout + (size_t)b * NQ * NS;
#pragma unroll
    for (int mt = 0; mt < 6; ++mt)
#pragma unroll
        for (int nt = 0; nt < 2; ++nt)
#pragma unroll
            for (int r = 0; r < 4; ++r) {
                int q = 16 * mt + 4 * lg + r;
                int s = s0 + 32 * wv + 16 * nt + ll;
                if (s < NS) aout[(size_t)q * NS + s] = acc[mt][nt][r];
            }
}

// ---------------- K15: in-place softmax over s (361) per (b,q) row of Aout ----------------
__global__ __launch_bounds__(256) void k15_softmaxs(float* __restrict__ Aout)
{
    const int b = blockIdx.x;
    const int q = blockIdx.y * 4 + (threadIdx.x >> 6);
    const int lane = threadIdx.x & 63;
    float* __restrict__ row = Aout + ((size_t)b * NQ + q) * NS;
    const int c0 = 6 * lane;

    float v[6];
    if (c0 + 5 < NS) {
        f32x4u_t t = *(const f32x4u_t*)(row + c0);
        v[0] = t[0]; v[1] = t[1]; v[2] = t[2]; v[3] = t[3];
        v[4] = row[c0 + 4]; v[5] = row[c0 + 5];
    } else {
#pragma unroll
        for (int i = 0; i < 6; ++i) v[i] = (c0 + i < NS) ? row[c0 + i] : -INFINITY;
    }
    float m = v[0];
#pragma unroll
    for (int i = 1; i < 6; ++i) m = fmaxf(m, v[i]);
#pragma unroll
    for (int o = 1; o < 64; o <<= 1) m = fmaxf(m, __shfl_xor(m, o));
    float e[6], sum = 0.0f;
#pragma unroll
    for (int i = 0; i < 6; ++i) { e[i] = __expf(v[i] - m); sum += e[i]; }
#pragma unroll
    for (int o = 1; o < 64; o <<= 1) sum += __shfl_xor(sum, o);
    float inv = 1.0f / sum;
    if (c0 + 5 < NS) {
        f32x4u_t t;
        t[0] = e[0] * inv; t[1] = e[1] * inv; t[2] = e[2] * inv; t[3] = e[3] * inv;
        *(f32x4u_t*)(row + c0) = t;
        row[c0 + 4] = e[4] * inv;
        row[c0 + 5] = e[5] * inv;
    } else {
#pragma unroll
        for (int i = 0; i < 6; ++i) if (c0 + i < NS) row[c0 + i] = e[i] * inv;
    }
}

// ---------------- K2: GEMM2 out[d][q] = sum_s ctx[d][s]*attn[q][s] ----------------
// grid = NB*4: block = (batch, d-quarter of 192). 512 threads = 8 waves (dw 0..3 x qw 0..1).
// attn staged bf16 in LDS; ctx A-fragments converted straight from global (no barriers in main loop).
__global__ __launch_bounds__(512, 4) void k3_gemm2(
    const float* __restrict__ Cg, const float* __restrict__ Aout, float* __restrict__ Wout)
{
    extern __shared__ char smem2[];
    unsigned short* sP = (unsigned short*)smem2;   // [96][LDP]
    unsigned* sPd = (unsigned*)smem2;              // dword view, row stride 196

    const int b = blockIdx.x >> 2;
    const int quarter = blockIdx.x & 3;
    const int tid  = threadIdx.x;
    const int wv   = tid >> 6;
    const int lane = tid & 63;
    const int ll = lane & 15;
    const int lg = lane >> 4;

    const float* __restrict__ attn = Aout + (size_t)b * NQ * NS;

    // fill attn rows as bf16 pairs (round-half-up), col 361 forced 0
    for (int i = tid; i < NQ * 181; i += 512) {
        int row = i / 181, p = i - row * 181;
        float x0 = attn[row * NS + 2 * p];
        float x1 = (p < 180) ? attn[row * NS + 2 * p + 1] : 0.0f;
        unsigned r0 = __float_as_uint(x0) + 0x8000u;
        unsigned r1 = __float_as_uint(x1) + 0x8000u;
        sPd[row * 196 + p] = pack_hi(r1, r0);
    }
    // zero pad cols 362..391 (dwords 181..195)
    for (int i = tid; i < NQ * 15; i += 512) {
        int row = i / 15, p = i - row * 15;
        sPd[row * 196 + 181 + p] = 0;
    }
    __syncthreads();

    f32x4_t acc[3][3];
#pragma unroll
    for (int i = 0; i < 3; ++i)
#pragma unroll
        for (int j = 0; j < 3; ++j) acc[i][j] = (f32x4_t)0.0f;

    const float* __restrict__ cq = Cg + (size_t)b * NDF * NS + (size_t)(quarter * 192) * NS;
    const int dw = wv >> 1, qw = wv & 1;

#pragma unroll
    for (int c = 0; c < 12; ++c) {
        bf16x8_t Bf[3];
#pragma unroll
        for (int nt = 0; nt < 3; ++nt) {
            int row = 16 * (3 * qw + nt) + ll;
            Bf[nt] = *(const bf16x8_t*)&sP[row * LDP + 32 * c + 8 * lg];   // 16B aligned, 2-way banks
        }
#pragma unroll
        for (int i = 0; i < 3; ++i) {
            int d = 16 * (3 * dw + i) + ll;
            const float* ap = cq + (size_t)d * NS + 32 * c + 8 * lg;
            u32x4_t u;
            if (c < 11) {
                f32x4u_t a0 = *(const f32x4u_t*)ap;
                f32x4u_t a1 = *(const f32x4u_t*)(ap + 4);
                u[0] = pack_hi(__float_as_uint(a0[1]), __float_as_uint(a0[0]));
                u[1] = pack_hi(__float_as_uint(a0[3]), __float_as_uint(a0[2]));
                u[2] = pack_hi(__float_as_uint(a1[1]), __float_as_uint(a1[0]));
                u[3] = pack_hi(__float_as_uint(a1[3]), __float_as_uint(a1[2]));
            } else {
                float t[8];
#pragma unroll
                for (int e = 0; e < 8; ++e) {
                    int s = 352 + 8 * lg + e;
                    t[e] = (s < NS) ? ap[e] : 0.0f;
                }
                u[0] = pack_hi(__float_as_uint(t[1]), __float_as_uint(t[0]));
                u[1] = pack_hi(__float_as_uint(t[3]), __float_as_uint(t[2]));
                u[2] = pack_hi(__float_as_uint(t[5]), __float_as_uint(t[4]));
                u[3] = pack_hi(__float_as_uint(t[7]), __float_as_uint(t[6]));
            }
            bf16x8_t Af = __builtin_bit_cast(bf16x8_t, u);
#pragma unroll
            for (int nt = 0; nt < 3; ++nt)
                acc[i][nt] = __builtin_amdgcn_mfma_f32_16x16x32_bf16(Af, Bf[nt], acc[i][nt], 0, 0, 0);
        }
    }

    float* wout = Wout + (size_t)b * NDF * NQ;
#pragma unroll
    for (int i = 0; i < 3; ++i)
#pragma unroll
        for (int nt = 0; nt < 3; ++nt)
#pragma unroll
            for (int r = 0; r < 4; ++r) {
                int d = quarter * 192 + 16 * (3 * dw + i) + 4 * lg + r;
                int q = 16 * (3 * qw + nt) + ll;
                wout[(size_t)d * NQ + q] = acc[i][nt][r];
            }
}

extern "C" void kernel_launch(void* const* d_in, const int* in_sizes, int n_in,
                              void* d_out, int out_size, void* d_ws, size_t ws_size,
                              hipStream_t stream) {
    const float* Qg = (const float*)d_in[0];
    const float* Cg = (const float*)d_in[1];
    float* Wout = (float*)d_out;
    float* Aout = Wout + (size_t)NB * NDF * NQ;   // outputs concatenated: weighted_context, attn_map

    hipLaunchKernelGGL(k1_gemm1_softmaxq, dim3(NB * 2), dim3(384), 0, stream, Qg, Cg, Aout);
    hipLaunchKernelGGL(k15_softmaxs, dim3(NB, 24), dim3(256), 0, stream, Aout);
    (void)hipFuncSetAttribute((const void*)k3_gemm2,
                              hipFuncAttributeMaxDynamicSharedMemorySize, NQ * LDP * 2);
    hipLaunchKernelGGL(k3_gemm2, dim3(NB * 4), dim3(512), NQ * LDP * 2, stream, Cg, Aout, Wout);
}

// Round 3
// 229.352 us; speedup vs baseline: 3.1278x; 1.1051x over previous
//
#include <hip/hip_runtime.h>

// Problem constants
#define NB 256
#define NDF 768
#define NQ 96
#define NS 361
#define LDT 40        // K1 staging stride (bf16 elems): 80B rows, 16B-aligned b128 frags
#define LDP 392       // K2 attn LDS stride (bf16 elems): 784B rows, 16B-aligned
#define WSROW 368     // ws row stride (bf16 elems): 184 dwords, 16B-aligned
#define WS_BYTES ((size_t)NB * NQ * WSROW * 2)

typedef short bf16x8_t __attribute__((ext_vector_type(8)));
typedef float f32x4_t __attribute__((ext_vector_type(4)));
typedef float f32x4u_t __attribute__((ext_vector_type(4), aligned(4)));
typedef unsigned int u32x2_t __attribute__((ext_vector_type(2)));
typedef unsigned int u32x4_t __attribute__((ext_vector_type(4)));

// [b.hi16 | a.hi16] -> one dword (1 v_perm_b32); trunc-to-bf16 pack
__device__ __forceinline__ unsigned pack_hi(unsigned b_, unsigned a_) {
    return __builtin_amdgcn_perm(b_, a_, 0x07060302u);
}
__device__ __forceinline__ unsigned short f2bf(float x) {   // RNE
    unsigned u = __float_as_uint(x);
    u += 0x7FFFu + ((u >> 16) & 1u);
    return (unsigned short)(u >> 16);
}
__device__ __forceinline__ float bf2f(unsigned short h) {
    return __uint_as_float(((unsigned)h) << 16);
}

// ================= K1: GEMM1 (split-bf16) + softmax over q =================
// grid NB*2 (batch, s-half of 192), 384 thr = 6 waves; wave: 2 s-tiles x 6 q-tiles.
// Async-stage: prefetch next K-chunk's global loads into regs before current MFMA.
template<bool WSP>
__global__ __launch_bounds__(384, 3) void k1_gemm1_softmaxq(
    const float* __restrict__ Qg, const float* __restrict__ Cg,
    unsigned short* __restrict__ Wsb, float* __restrict__ AoutF)
{
    __shared__ unsigned short sQhi[NQ * LDT];
    __shared__ unsigned short sQlo[NQ * LDT];
    __shared__ unsigned short sShi[192 * LDT];
    __shared__ unsigned short sSlo[192 * LDT];

    const int b = blockIdx.x >> 1;
    const int h = blockIdx.x & 1;
    const int tid = threadIdx.x;
    const int wv = tid >> 6;
    const int lane = tid & 63;
    const int ll = lane & 15;
    const int lg = lane >> 4;
    const int s0 = 192 * h;
    // Q staging geometry: quad (4 k-rows, 1 q); thread does quads kqQ and kqQ+4
    const int qq  = tid % NQ;
    const int kqQ = tid / NQ;          // 0..3
    // C staging geometry: quad (4 k-rows, 1 s); thread does quads kqC+2j, j=0..3
    const int ssb = tid % 192;
    const int kqC = tid / 192;         // 0..1
    const int sAbs = s0 + ssb;
    const bool okC = (sAbs < NS);

    const float* __restrict__ qg = Qg + (size_t)b * NDF * NQ;   // [768][96]
    const float* __restrict__ cg = Cg + (size_t)b * NDF * NS;   // [768][361]

    f32x4_t acc[6][2];
#pragma unroll
    for (int i = 0; i < 6; ++i)
#pragma unroll
        for (int j = 0; j < 2; ++j) acc[i][j] = (f32x4_t)0.0f;

    float RQa[8], RCa[16], RQb[8], RCb[16];

#define LOADQ(K0, R) { \
    const float* p = qg + ((K0) + 4 * kqQ) * NQ + qq; \
    R[0] = p[0]; R[1] = p[NQ]; R[2] = p[2 * NQ]; R[3] = p[3 * NQ]; \
    const float* p2 = p + 16 * NQ; \
    R[4] = p2[0]; R[5] = p2[NQ]; R[6] = p2[2 * NQ]; R[7] = p2[3 * NQ]; }

#define LOADC(K0, R) { \
    const float* p = cg + ((K0) + 4 * kqC) * NS + sAbs; \
    _Pragma("unroll") \
    for (int j = 0; j < 4; ++j) { \
        const float* pj = p + j * 8 * NS; \
        R[4*j+0] = okC ? pj[0] : 0.0f; \
        R[4*j+1] = okC ? pj[NS] : 0.0f; \
        R[4*j+2] = okC ? pj[2*NS] : 0.0f; \
        R[4*j+3] = okC ? pj[3*NS] : 0.0f; } }

#define STOREQC(RQ, RC) { \
    _Pragma("unroll") \
    for (int t = 0; t < 2; ++t) { \
        unsigned u0 = __float_as_uint(RQ[4*t+0]), u1 = __float_as_uint(RQ[4*t+1]); \
        unsigned u2 = __float_as_uint(RQ[4*t+2]), u3 = __float_as_uint(RQ[4*t+3]); \
        float l0 = RQ[4*t+0] - __uint_as_float(u0 & 0xFFFF0000u); \
        float l1 = RQ[4*t+1] - __uint_as_float(u1 & 0xFFFF0000u); \
        float l2 = RQ[4*t+2] - __uint_as_float(u2 & 0xFFFF0000u); \
        float l3 = RQ[4*t+3] - __uint_as_float(u3 & 0xFFFF0000u); \
        u32x2_t hi, lo; \
        hi[0] = pack_hi(u1, u0); hi[1] = pack_hi(u3, u2); \
        lo[0] = pack_hi(__float_as_uint(l1), __float_as_uint(l0)); \
        lo[1] = pack_hi(__float_as_uint(l3), __float_as_uint(l2)); \
        int off = qq * LDT + 4 * (kqQ + 4 * t); \
        *(u32x2_t*)&sQhi[off] = hi; \
        *(u32x2_t*)&sQlo[off] = lo; } \
    _Pragma("unroll") \
    for (int j = 0; j < 4; ++j) { \
        unsigned u0 = __float_as_uint(RC[4*j+0]), u1 = __float_as_uint(RC[4*j+1]); \
        unsigned u2 = __float_as_uint(RC[4*j+2]), u3 = __float_as_uint(RC[4*j+3]); \
        float l0 = RC[4*j+0] - __uint_as_float(u0 & 0xFFFF0000u); \
        float l1 = RC[4*j+1] - __uint_as_float(u1 & 0xFFFF0000u); \
        float l2 = RC[4*j+2] - __uint_as_float(u2 & 0xFFFF0000u); \
        float l3 = RC[4*j+3] - __uint_as_float(u3 & 0xFFFF0000u); \
        u32x2_t hi, lo; \
        hi[0] = pack_hi(u1, u0); hi[1] = pack_hi(u3, u2); \
        lo[0] = pack_hi(__float_as_uint(l1), __float_as_uint(l0)); \
        lo[1] = pack_hi(__float_as_uint(l3), __float_as_uint(l2)); \
        int off = ssb * LDT + 4 * (kqC + 2 * j); \
        *(u32x2_t*)&sShi[off] = hi; \
        *(u32x2_t*)&sSlo[off] = lo; } }

#define FRAGMFMA() { \
    bf16x8_t Bhi[2], Blo[2]; \
    _Pragma("unroll") \
    for (int nt = 0; nt < 2; ++nt) { \
        int row = 32 * wv + 16 * nt + ll; \
        Bhi[nt] = *(const bf16x8_t*)&sShi[row * LDT + 8 * lg]; \
        Blo[nt] = *(const bf16x8_t*)&sSlo[row * LDT + 8 * lg]; } \
    _Pragma("unroll") \
    for (int mt = 0; mt < 6; ++mt) { \
        int row = 16 * mt + ll; \
        bf16x8_t Ahi = *(const bf16x8_t*)&sQhi[row * LDT + 8 * lg]; \
        bf16x8_t Alo = *(const bf16x8_t*)&sQlo[row * LDT + 8 * lg]; \
        _Pragma("unroll") \
        for (int nt = 0; nt < 2; ++nt) { \
            acc[mt][nt] = __builtin_amdgcn_mfma_f32_16x16x32_bf16(Ahi, Bhi[nt], acc[mt][nt], 0, 0, 0); \
            acc[mt][nt] = __builtin_amdgcn_mfma_f32_16x16x32_bf16(Ahi, Blo[nt], acc[mt][nt], 0, 0, 0); \
            acc[mt][nt] = __builtin_amdgcn_mfma_f32_16x16x32_bf16(Alo, Bhi[nt], acc[mt][nt], 0, 0, 0); } } }

    LOADQ(0, RQa); LOADC(0, RCa);
    for (int k0 = 0; k0 < NDF; k0 += 64) {
        STOREQC(RQa, RCa);
        __syncthreads();
        if (k0 + 32 < NDF) { LOADQ(k0 + 32, RQb); LOADC(k0 + 32, RCb); }
        FRAGMFMA();
        __syncthreads();
        STOREQC(RQb, RCb);
        __syncthreads();
        if (k0 + 64 < NDF) { LOADQ(k0 + 64, RQa); LOADC(k0 + 64, RCa); }
        FRAGMFMA();
        __syncthreads();
    }
#undef LOADQ
#undef LOADC
#undef STOREQC
#undef FRAGMFMA

    // softmax over q (per s-col), fold *4; D layout: col(s)=ll, row(q)=16mt+4lg+r
#pragma unroll
    for (int nt = 0; nt < 2; ++nt) {
        float m = -3.0e38f;
#pragma unroll
        for (int mt = 0; mt < 6; ++mt)
#pragma unroll
            for (int r = 0; r < 4; ++r) m = fmaxf(m, acc[mt][nt][r]);
        m = fmaxf(m, __shfl_xor(m, 16));
        m = fmaxf(m, __shfl_xor(m, 32));
        float sum = 0.0f;
#pragma unroll
        for (int mt = 0; mt < 6; ++mt)
#pragma unroll
            for (int r = 0; r < 4; ++r) {
                float e = __expf(acc[mt][nt][r] - m);
                acc[mt][nt][r] = e;
                sum += e;
            }
        sum += __shfl_xor(sum, 16);
        sum += __shfl_xor(sum, 32);
        float inv = 4.0f / sum;     // fold TEMP1
#pragma unroll
        for (int mt = 0; mt < 6; ++mt)
#pragma unroll
            for (int r = 0; r < 4; ++r) acc[mt][nt][r] *= inv;
    }

    if constexpr (WSP) {
        unsigned short* wr = Wsb + (size_t)b * NQ * WSROW;
#pragma unroll
        for (int mt = 0; mt < 6; ++mt)
#pragma unroll
            for (int nt = 0; nt < 2; ++nt)
#pragma unroll
                for (int r = 0; r < 4; ++r) {
                    int q = 16 * mt + 4 * lg + r;
                    int s = s0 + 32 * wv + 16 * nt + ll;
                    if (s < NS) wr[q * WSROW + s] = f2bf(acc[mt][nt][r]);
                }
    } else {
        float* aout = AoutF + (size_t)b * NQ * NS;
#pragma unroll
        for (int mt = 0; mt < 6; ++mt)
#pragma unroll
            for (int nt = 0; nt < 2; ++nt)
#pragma unroll
                for (int r = 0; r < 4; ++r) {
                    int q = 16 * mt + 4 * lg + r;
                    int s = s0 + 32 * wv + 16 * nt + ll;
                    if (s < NS) aout[(size_t)q * NS + s] = acc[mt][nt][r];
                }
    }
}

// ================= K15 (fallback only): in-place softmax over s =================
__global__ __launch_bounds__(256) void k15_softmaxs(float* __restrict__ Aout)
{
    const int b = blockIdx.x;
    const int q = blockIdx.y * 4 + (threadIdx.x >> 6);
    const int lane = threadIdx.x & 63;
    float* __restrict__ row = Aout + ((size_t)b * NQ + q) * NS;
    const int c0 = 6 * lane;

    float v[6];
    if (c0 + 5 < NS) {
        f32x4u_t t = *(const f32x4u_t*)(row + c0);
        v[0] = t[0]; v[1] = t[1]; v[2] = t[2]; v[3] = t[3];
        v[4] = row[c0 + 4]; v[5] = row[c0 + 5];
    } else {
#pragma unroll
        for (int i = 0; i < 6; ++i) v[i] = (c0 + i < NS) ? row[c0 + i] : -INFINITY;
    }
    float m = v[0];
#pragma unroll
    for (int i = 1; i < 6; ++i) m = fmaxf(m, v[i]);
#pragma unroll
    for (int o = 1; o < 64; o <<= 1) m = fmaxf(m, __shfl_xor(m, o));
    float e[6], sum = 0.0f;
#pragma unroll
    for (int i = 0; i < 6; ++i) { e[i] = __expf(v[i] - m); sum += e[i]; }
#pragma unroll
    for (int o = 1; o < 64; o <<= 1) sum += __shfl_xor(sum, o);
    float inv = 1.0f / sum;
#pragma unroll
    for (int i = 0; i < 6; ++i) if (c0 + i < NS) row[c0 + i] = e[i] * inv;
}

// ================= K2: [fused softmax-s +] GEMM2 =================
// grid NB*4 (batch, d-quarter of 192), 512 thr = 8 waves (dw 0..3 x qw 0..1).
template<bool FUSED>
__global__ __launch_bounds__(512, 4) void k2_gemm2(
    const float* __restrict__ Cg, const unsigned short* __restrict__ Wsb,
    const float* __restrict__ AttnF, float* __restrict__ Wout, float* __restrict__ AoutF)
{
    extern __shared__ char smem2[];
    unsigned short* sP = (unsigned short*)smem2;      // [96][LDP]
    unsigned* sPd = (unsigned*)smem2;                 // dword view, stride 196
    float* sMax = (float*)(smem2 + NQ * LDP * 2);     // [96]
    float* sInv = sMax + NQ;                          // [96]

    const int b = blockIdx.x >> 2;
    const int quarter = blockIdx.x & 3;
    const int tid = threadIdx.x;
    const int wv = tid >> 6;
    const int lane = tid & 63;
    const int ll = lane & 15;
    const int lg = lane >> 4;

    if constexpr (FUSED) {
        // stage raw bf16 logits2 from ws; elems >=361 are garbage (masked below)
        const unsigned* __restrict__ wsd = (const unsigned*)(Wsb + (size_t)b * NQ * WSROW);
        for (int i = tid; i < NQ * 184; i += 512) {
            int r = i / 184, c = i - r * 184;
            sPd[r * 196 + c] = wsd[i];
        }
        for (int i = tid; i < NQ * 12; i += 512) {     // zero pad dwords 184..195
            int r = i / 12, c = i - r * 12;
            sPd[r * 196 + 184 + c] = 0;
        }
        __syncthreads();

        const int l32 = tid & 31;
        const int rbase = tid >> 5;    // 0..15
        // ---- max pass (per q-row over s) ----
#pragma unroll
        for (int pass = 0; pass < 6; ++pass) {
            int row = pass * 16 + rbase;
            float m = -3.0e38f;
#pragma unroll
            for (int j = 0; j < 6; ++j) {
                int dw = l32 + 32 * j;
                if (dw < 184) {
                    unsigned u = sPd[row * 196 + dw];
                    float v0 = bf2f((unsigned short)(u & 0xFFFFu));
                    float v1 = bf2f((unsigned short)(u >> 16));
                    if (2 * dw < NS) m = fmaxf(m, v0);
                    if (2 * dw + 1 < NS) m = fmaxf(m, v1);
                }
            }
#pragma unroll
            for (int o = 1; o < 32; o <<= 1) m = fmaxf(m, __shfl_xor(m, o));
            if (l32 == 0) sMax[row] = m;
        }
        __syncthreads();
        // ---- exp pass: store unnormalized exp as bf16; row sums ----
#pragma unroll
        for (int pass = 0; pass < 6; ++pass) {
            int row = pass * 16 + rbase;
            float m = sMax[row];
            float sum = 0.0f;
#pragma unroll
            for (int j = 0; j < 6; ++j) {
                int dw = l32 + 32 * j;
                if (dw < 184) {
                    unsigned u = sPd[row * 196 + dw];
                    float v0 = bf2f((unsigned short)(u & 0xFFFFu));
                    float v1 = bf2f((unsigned short)(u >> 16));
                    float e0 = (2 * dw < NS) ? __expf(v0 - m) : 0.0f;
                    float e1 = (2 * dw + 1 < NS) ? __expf(v1 - m) : 0.0f;
                    sum += e0 + e1;
                    sPd[row * 196 + dw] = ((unsigned)f2bf(e1) << 16) | (unsigned)f2bf(e0);
                }
            }
#pragma unroll
            for (int o = 1; o < 32; o <<= 1) sum += __shfl_xor(sum, o);
            if (l32 == 0) sInv[row] = sum;
        }
        __syncthreads();
        if (tid < NQ) sInv[tid] = 1.0f / sInv[tid];
        __syncthreads();
        if (quarter == 0) {   // write attn_map once per batch
            float* aout = AoutF + (size_t)b * NQ * NS;
            for (int i = tid; i < NQ * NS; i += 512) {
                int q = i / NS, s = i - q * NS;
                aout[i] = bf2f(sP[q * LDP + s]) * sInv[q];
            }
        }
    } else {
        // stage softmaxed fp32 attn -> bf16 (round-half-up)
        const float* __restrict__ attn = AttnF + (size_t)b * NQ * NS;
        for (int i = tid; i < NQ * 181; i += 512) {
            int row = i / 181, p = i - row * 181;
            float x0 = attn[row * NS + 2 * p];
            float x1 = (p < 180) ? attn[row * NS + 2 * p + 1] : 0.0f;
            unsigned r0 = __float_as_uint(x0) + 0x8000u;
            unsigned r1 = __float_as_uint(x1) + 0x8000u;
            sPd[row * 196 + p] = pack_hi(r1, r0);
        }
        for (int i = tid; i < NQ * 15; i += 512) {
            int row = i / 15, p = i - row * 15;
            sPd[row * 196 + 181 + p] = 0;
        }
        __syncthreads();
    }

    // ---- GEMM2 main loop: A = ctx rows (direct from global, trunc->bf16), B = sP ----
    f32x4_t acc[3][3];
#pragma unroll
    for (int i = 0; i < 3; ++i)
#pragma unroll
        for (int j = 0; j < 3; ++j) acc[i][j] = (f32x4_t)0.0f;

    const float* __restrict__ cq = Cg + (size_t)b * NDF * NS + (size_t)(quarter * 192) * NS;
    const int dw = wv >> 1, qw = wv & 1;

#pragma unroll
    for (int c = 0; c < 12; ++c) {
        bf16x8_t Bf[3];
#pragma unroll
        for (int nt = 0; nt < 3; ++nt) {
            int row = 16 * (3 * qw + nt) + ll;
            Bf[nt] = *(const bf16x8_t*)&sP[row * LDP + 32 * c + 8 * lg];
        }
#pragma unroll
        for (int i = 0; i < 3; ++i) {
            int d = 16 * (3 * dw + i) + ll;
            const float* ap = cq + (size_t)d * NS + 32 * c + 8 * lg;
            u32x4_t u;
            if (c < 11) {
                f32x4u_t a0 = *(const f32x4u_t*)ap;
                f32x4u_t a1 = *(const f32x4u_t*)(ap + 4);
                u[0] = pack_hi(__float_as_uint(a0[1]), __float_as_uint(a0[0]));
                u[1] = pack_hi(__float_as_uint(a0[3]), __float_as_uint(a0[2]));
                u[2] = pack_hi(__float_as_uint(a1[1]), __float_as_uint(a1[0]));
                u[3] = pack_hi(__float_as_uint(a1[3]), __float_as_uint(a1[2]));
            } else {
                float t[8];
#pragma unroll
                for (int e = 0; e < 8; ++e) {
                    int s = 352 + 8 * lg + e;
                    t[e] = (s < NS) ? ap[e] : 0.0f;
                }
                u[0] = pack_hi(__float_as_uint(t[1]), __float_as_uint(t[0]));
                u[1] = pack_hi(__float_as_uint(t[3]), __float_as_uint(t[2]));
                u[2] = pack_hi(__float_as_uint(t[5]), __float_as_uint(t[4]));
                u[3] = pack_hi(__float_as_uint(t[7]), __float_as_uint(t[6]));
            }
            bf16x8_t Af = __builtin_bit_cast(bf16x8_t, u);
#pragma unroll
            for (int nt = 0; nt < 3; ++nt)
                acc[i][nt] = __builtin_amdgcn_mfma_f32_16x16x32_bf16(Af, Bf[nt], acc[i][nt], 0, 0, 0);
        }
    }

    float* wout = Wout + (size_t)b * NDF * NQ;
    float invq[3];
#pragma unroll
    for (int nt = 0; nt < 3; ++nt) {
        if constexpr (FUSED) invq[nt] = sInv[16 * (3 * qw + nt) + ll];
        else invq[nt] = 1.0f;
    }
#pragma unroll
    for (int i = 0; i < 3; ++i)
#pragma unroll
        for (int nt = 0; nt < 3; ++nt)
#pragma unroll
            for (int r = 0; r < 4; ++r) {
                int d = quarter * 192 + 16 * (3 * dw + i) + 4 * lg + r;
                int q = 16 * (3 * qw + nt) + ll;
                wout[(size_t)d * NQ + q] = acc[i][nt][r] * invq[nt];
            }
}

extern "C" void kernel_launch(void* const* d_in, const int* in_sizes, int n_in,
                              void* d_out, int out_size, void* d_ws, size_t ws_size,
                              hipStream_t stream) {
    const float* Qg = (const float*)d_in[0];
    const float* Cg = (const float*)d_in[1];
    float* Wout = (float*)d_out;
    float* Aout = Wout + (size_t)NB * NDF * NQ;   // outputs: weighted_context, attn_map

    const int smem2 = NQ * LDP * 2 + NQ * 8;      // 76032 B

    if (ws_size >= WS_BYTES) {
        unsigned short* wsb = (unsigned short*)d_ws;
        k1_gemm1_softmaxq<true><<<dim3(NB * 2), dim3(384), 0, stream>>>(Qg, Cg, wsb, nullptr);
        (void)hipFuncSetAttribute((const void*)k2_gemm2<true>,
                                  hipFuncAttributeMaxDynamicSharedMemorySize, smem2);
        k2_gemm2<true><<<dim3(NB * 4), dim3(512), smem2, stream>>>(Cg, wsb, nullptr, Wout, Aout);
    } else {
        k1_gemm1_softmaxq<false><<<dim3(NB * 2), dim3(384), 0, stream>>>(Qg, Cg, nullptr, Aout);
        k15_softmaxs<<<dim3(NB, 24), dim3(256), 0, stream>>>(Aout);
        (void)hipFuncSetAttribute((const void*)k2_gemm2<false>,
                                  hipFuncAttributeMaxDynamicSharedMemorySize, smem2);
        k2_gemm2<false><<<dim3(NB * 4), dim3(512), smem2, stream>>>(Cg, nullptr, Aout, Wout, Aout);
    }
}